// Round 5
// baseline (380.516 us; speedup 1.0000x reference)
//
#include <hip/hip_runtime.h>
#include <math.h>

typedef unsigned short u16;
typedef __attribute__((ext_vector_type(8))) short short8;     // 8 bf16 = one MFMA A/B frag
typedef __attribute__((ext_vector_type(4))) float floatx4;    // MFMA C/D frag
typedef __attribute__((ext_vector_type(4))) unsigned short ushort4v;
typedef __attribute__((ext_vector_type(2))) unsigned int uint2v;

// ---------- bf16 helpers (raw u16, RNE) ----------
__device__ __forceinline__ float bf2f(u16 x) {
    union { unsigned int u; float f; } v; v.u = ((unsigned int)x) << 16; return v.f;
}
__device__ __forceinline__ u16 f2bf(float f) {
    union { float f; unsigned int u; } v; v.f = f;
    unsigned int r = v.u + 0x7fffu + ((v.u >> 16) & 1u);
    return (u16)(r >> 16);
}
__device__ __forceinline__ unsigned int pk2bf(float a, float b) {
#if __has_builtin(__builtin_amdgcn_cvt_pk_bf16_f32)
    auto r = __builtin_amdgcn_cvt_pk_bf16_f32(a, b);
    union { decltype(r) v; unsigned int u; } cv; cv.v = r; return cv.u;
#else
    return (unsigned int)f2bf(a) | ((unsigned int)f2bf(b) << 16);
#endif
}
// pack 8 fp32 -> short8 (8 bf16)
__device__ __forceinline__ short8 cvt8(const floatx4 a, const floatx4 b) {
    union { unsigned int u[4]; short8 s; } r;
    r.u[0] = pk2bf(a[0], a[1]); r.u[1] = pk2bf(a[2], a[3]);
    r.u[2] = pk2bf(b[0], b[1]); r.u[3] = pk2bf(b[2], b[3]);
    return r.s;
}

// =====================================================================
// wfuse: w_z[row] = dot(W_z[row][:], wv_z[:]) ; block x==0 also emits
// bdot[z] = dot(bl_z, wv_z).  grid (64, 4).
// =====================================================================
struct WFuseJobs { const float* W[4]; const float* wv[4]; const float* bl[4];
                   float* out[4]; float* bdot; };

__global__ __launch_bounds__(256) void wfuse(WFuseJobs wf) {
    const int z = blockIdx.y;
    const float* W = wf.W[z];
    const float* wv = wf.wv[z];
    float* out = wf.out[z];
    const int t = threadIdx.x;
    const int lane = t & 63, w = t >> 6;
#pragma unroll
    for (int i = 0; i < 4; i++) {
        const int row = blockIdx.x * 16 + w * 4 + i;
        const float* Wr = W + (size_t)row * 1024 + lane * 16;
        const float* vr = wv + lane * 16;
        float p = 0.f;
#pragma unroll
        for (int c = 0; c < 4; c++) {
            const floatx4 a = *(const floatx4*)(Wr + c * 4);
            const floatx4 b = *(const floatx4*)(vr + c * 4);
            p += a[0] * b[0] + a[1] * b[1] + a[2] * b[2] + a[3] * b[3];
        }
#pragma unroll
        for (int m = 1; m <= 32; m <<= 1) p += __shfl_xor(p, m);
        if (lane == 0) out[row] = p;
    }
    if (blockIdx.x == 0) {
        const floatx4 bb = *(const floatx4*)(wf.bl[z] + t * 4);
        const floatx4 vv = *(const floatx4*)(wv + t * 4);
        float p = bb[0] * vv[0] + bb[1] * vv[1] + bb[2] * vv[2] + bb[3] * vv[3];
#pragma unroll
        for (int m = 1; m <= 32; m <<= 1) p += __shfl_xor(p, m);
        __shared__ float red[4];
        if ((t & 63) == 0) red[t >> 6] = p;
        __syncthreads();
        if (t == 0) wf.bdot[z] = red[0] + red[1] + red[2] + red[3];
    }
}

// =====================================================================
// dotk: lam[z][row] = sigmoid(xa[row].w1 + xc[row].w2 + bdot-consts + s)
// grid (4096 rows, 2 z). Reads fp32 inputs directly.
// =====================================================================
struct DotJobs {
    const float* xa[2]; const float* xc[2];
    const float* w1[2]; const float* w2[2];
    const float* bdot;                 // 4 scalars (z pairs: 2z, 2z+1)
    const float* sA[2]; const float* sB[2];
    float* lam[2];
};

__global__ __launch_bounds__(256) void dotk(DotJobs dj) {
    const int z = blockIdx.y;
    const int row = blockIdx.x;
    const int t = threadIdx.x;
    const size_t off = (size_t)row * 1024 + t * 4;
    const floatx4 a  = *(const floatx4*)(dj.xa[z] + off);
    const floatx4 c  = *(const floatx4*)(dj.xc[z] + off);
    const floatx4 w1 = *(const floatx4*)(dj.w1[z] + t * 4);
    const floatx4 w2 = *(const floatx4*)(dj.w2[z] + t * 4);
    float p = 0.f;
#pragma unroll
    for (int j = 0; j < 4; j++) p += a[j] * w1[j] + c[j] * w2[j];
#pragma unroll
    for (int m = 1; m <= 32; m <<= 1) p += __shfl_xor(p, m);
    __shared__ float red[4];
    if ((t & 63) == 0) red[t >> 6] = p;
    __syncthreads();
    if (t == 0) {
        const float x = red[0] + red[1] + red[2] + red[3]
                      + dj.bdot[2 * z] + dj.bdot[2 * z + 1]
                      + dj.sA[z][0] + dj.sB[z][0];
        dj.lam[z][row] = 1.f / (1.f + exp2f(-x * 1.44269504f));
    }
}

// =====================================================================
// transpose + cast 6 weight matrices: W[k][n] fp32 -> Wt[n][k] bf16
// =====================================================================
struct WTJobs { const float* src[6]; u16* dst[6]; };

__global__ __launch_bounds__(256) void wtrans(WTJobs wj) {
    __shared__ float tile[32][33];
    const int z = blockIdx.z;
    const float* W = wj.src[z];
    u16* Wt = wj.dst[z];
    const int n0 = blockIdx.x * 32, k0 = blockIdx.y * 32;
    const int tx = threadIdx.x & 31, ty = threadIdx.x >> 5;
#pragma unroll
    for (int i = 0; i < 4; i++)
        tile[ty + i * 8][tx] = W[(size_t)(k0 + ty + i * 8) * 1024 + n0 + tx];
    __syncthreads();
#pragma unroll
    for (int i = 0; i < 4; i++)
        Wt[(size_t)(n0 + ty + i * 8) * 1024 + k0 + tx] = f2bf(tile[tx][ty + i * 8]);
}

// =====================================================================
// transpose V: V[s][base+d] (stride 2048) -> Vtg[(bh*64+d)*2048 + s], bf16
// =====================================================================
__global__ __launch_bounds__(256) void vtrans(const u16* __restrict__ V,
                                              u16* __restrict__ Vtg) {
    __shared__ u16 tile[32][34];
    const int bh = blockIdx.z, b = bh >> 4, h = bh & 15;
    const int base = b * 1024 + h * 64;
    const int s0 = blockIdx.x * 32, d0 = blockIdx.y * 32;
    const int tx = threadIdx.x & 31, ty = threadIdx.x >> 5;
#pragma unroll
    for (int i = 0; i < 4; i++)
        tile[ty + i * 8][tx] = V[(size_t)(s0 + ty + i * 8) * 2048 + base + d0 + tx];
    __syncthreads();
#pragma unroll
    for (int i = 0; i < 4; i++)
        Vtg[((size_t)bh * 64 + d0 + ty + i * 8) * 2048 + s0 + tx] = tile[tx][ty + i * 8];
}

// =====================================================================
// projall v2: fp32-A projection GEMMs with all-register prefetch staging.
// dual mode: out = (1-lam)*(Aa@Ba^T+biasA) + lam*(Ac@Bc^T+biasC)
// single:    out = Aa@Ba^T + biasA
// 128x128 tile, BK=32. grid (8, 32, 3): z=0 q-dual, z=1 k-dual, z=2 v.
// Staging: A fp32 from global -> regs -> cvt -> ds_write_b128;
// B bf16 -> regs -> ds_write_b128. Next tile's loads issued before the
// compute barrier so they retire during the MFMA phase (attn4 pattern).
// =====================================================================
struct PJob {
    const float* Aa; const float* Ac; const u16* Ba; const u16* Bc;
    const float* biasA; const float* biasC; const float* lam; u16* out;
};
struct PJobs { PJob j[3]; };

__global__ __launch_bounds__(256, 2) void projall(PJobs jobs) {
    __shared__ u16 Asa[128 * 32];
    __shared__ u16 Asc[128 * 32];
    __shared__ u16 Bsa[128 * 32];
    __shared__ u16 Bsc[128 * 32];
    const PJob jb = jobs.j[blockIdx.z];
    const int K = 1024;
    const int m0 = blockIdx.y * 128;
    const int n0 = blockIdx.x * 128;
    const int t = threadIdx.x;
    const int lane = t & 63;
    const int wid = t >> 6;
    const int wm = wid >> 1, wn = wid & 1;
    const int qd = lane >> 4, lm = lane & 15;

    // staging coords: thread t covers row = t>>1, cols colb..colb+15
    const int srow = t >> 1, colb = (t & 1) * 16;
    const float* Aap = jb.Aa + (size_t)(m0 + srow) * K + colb;
    const u16*   Bap = jb.Ba + (size_t)(n0 + srow) * K + colb;
    u16* awr  = &Asa[srow * 32 + colb];
    u16* cwr  = &Asc[srow * 32 + colb];
    u16* bawr = &Bsa[srow * 32 + colb];
    u16* bcwr = &Bsc[srow * 32 + colb];

    const floatx4 zero4 = {0.f, 0.f, 0.f, 0.f};

    if (jb.Ac) {
        // ---------------- dual mode ----------------
        floatx4 accA[4][4], accC[4][4];
#pragma unroll
        for (int i = 0; i < 4; i++)
#pragma unroll
            for (int j2 = 0; j2 < 4; j2++) { accA[i][j2] = zero4; accC[i][j2] = zero4; }
        const float* Acp = jb.Ac + (size_t)(m0 + srow) * K + colb;
        const u16*   Bcp = jb.Bc + (size_t)(n0 + srow) * K + colb;

        // prefetch tile 0
        floatx4 pa[4], pc[4];
        short8 pba[2], pbc[2];
#pragma unroll
        for (int q = 0; q < 4; q++) { pa[q] = *(const floatx4*)(Aap + q * 4); pc[q] = *(const floatx4*)(Acp + q * 4); }
        pba[0] = *(const short8*)Bap; pba[1] = *(const short8*)(Bap + 8);
        pbc[0] = *(const short8*)Bcp; pbc[1] = *(const short8*)(Bcp + 8);

        for (int k0 = 0; k0 < K; k0 += 32) {
            __syncthreads();
            *(short8*)awr        = cvt8(pa[0], pa[1]);
            *(short8*)(awr + 8)  = cvt8(pa[2], pa[3]);
            *(short8*)cwr        = cvt8(pc[0], pc[1]);
            *(short8*)(cwr + 8)  = cvt8(pc[2], pc[3]);
            *(short8*)bawr       = pba[0];
            *(short8*)(bawr + 8) = pba[1];
            *(short8*)bcwr       = pbc[0];
            *(short8*)(bcwr + 8) = pbc[1];
            if (k0 + 32 < K) {
                Aap += 32; Acp += 32; Bap += 32; Bcp += 32;
#pragma unroll
                for (int q = 0; q < 4; q++) { pa[q] = *(const floatx4*)(Aap + q * 4); pc[q] = *(const floatx4*)(Acp + q * 4); }
                pba[0] = *(const short8*)Bap; pba[1] = *(const short8*)(Bap + 8);
                pbc[0] = *(const short8*)Bcp; pbc[1] = *(const short8*)(Bcp + 8);
            }
            __syncthreads();

            short8 aa[4], ac[4], ba[4], bc[4];
#pragma unroll
            for (int i = 0; i < 4; i++) {
                aa[i] = *(const short8*)&Asa[(wm * 64 + i * 16 + lm) * 32 + qd * 8];
                ac[i] = *(const short8*)&Asc[(wm * 64 + i * 16 + lm) * 32 + qd * 8];
                ba[i] = *(const short8*)&Bsa[(wn * 64 + i * 16 + lm) * 32 + qd * 8];
                bc[i] = *(const short8*)&Bsc[(wn * 64 + i * 16 + lm) * 32 + qd * 8];
            }
#pragma unroll
            for (int i = 0; i < 4; i++)
#pragma unroll
                for (int j2 = 0; j2 < 4; j2++) {
                    accA[i][j2] = __builtin_amdgcn_mfma_f32_16x16x32_bf16(aa[i], ba[j2], accA[i][j2], 0, 0, 0);
                    accC[i][j2] = __builtin_amdgcn_mfma_f32_16x16x32_bf16(ac[i], bc[j2], accC[i][j2], 0, 0, 0);
                }
        }

#pragma unroll
        for (int i = 0; i < 4; i++) {
            const int mb = m0 + wm * 64 + i * 16 + qd * 4;
            float lamv[4];
#pragma unroll
            for (int r = 0; r < 4; r++) lamv[r] = jb.lam[mb + r];
#pragma unroll
            for (int j2 = 0; j2 < 4; j2++) {
                const int col = n0 + wn * 64 + j2 * 16 + lm;
                const float bA = jb.biasA[col];
                const float bC = jb.biasC[col];
#pragma unroll
                for (int r = 0; r < 4; r++) {
                    const float va = accA[i][j2][r] + bA;
                    const float vc = accC[i][j2][r] + bC;
                    jb.out[(size_t)(mb + r) * 1024 + col] = f2bf(va + lamv[r] * (vc - va));
                }
            }
        }
    } else {
        // ---------------- single mode ----------------
        floatx4 acc[4][4];
#pragma unroll
        for (int i = 0; i < 4; i++)
#pragma unroll
            for (int j2 = 0; j2 < 4; j2++) acc[i][j2] = zero4;

        floatx4 pa[4];
        short8 pba[2];
#pragma unroll
        for (int q = 0; q < 4; q++) pa[q] = *(const floatx4*)(Aap + q * 4);
        pba[0] = *(const short8*)Bap; pba[1] = *(const short8*)(Bap + 8);

        for (int k0 = 0; k0 < K; k0 += 32) {
            __syncthreads();
            *(short8*)awr        = cvt8(pa[0], pa[1]);
            *(short8*)(awr + 8)  = cvt8(pa[2], pa[3]);
            *(short8*)bawr       = pba[0];
            *(short8*)(bawr + 8) = pba[1];
            if (k0 + 32 < K) {
                Aap += 32; Bap += 32;
#pragma unroll
                for (int q = 0; q < 4; q++) pa[q] = *(const floatx4*)(Aap + q * 4);
                pba[0] = *(const short8*)Bap; pba[1] = *(const short8*)(Bap + 8);
            }
            __syncthreads();

            short8 af[4], bfg[4];
#pragma unroll
            for (int i = 0; i < 4; i++) {
                af[i]  = *(const short8*)&Asa[(wm * 64 + i * 16 + lm) * 32 + qd * 8];
                bfg[i] = *(const short8*)&Bsa[(wn * 64 + i * 16 + lm) * 32 + qd * 8];
            }
#pragma unroll
            for (int i = 0; i < 4; i++)
#pragma unroll
                for (int j2 = 0; j2 < 4; j2++)
                    acc[i][j2] = __builtin_amdgcn_mfma_f32_16x16x32_bf16(af[i], bfg[j2], acc[i][j2], 0, 0, 0);
        }

#pragma unroll
        for (int i = 0; i < 4; i++) {
            const int mb = m0 + wm * 64 + i * 16 + qd * 4;
#pragma unroll
            for (int j2 = 0; j2 < 4; j2++) {
                const int col = n0 + wn * 64 + j2 * 16 + lm;
                const float bv = jb.biasA[col];
#pragma unroll
                for (int r = 0; r < 4; r++)
                    jb.out[(size_t)(mb + r) * 1024 + col] = f2bf(acc[i][j2][r] + bv);
            }
        }
    }
}

// =====================================================================
// gemm64: C_f32[M,1024] = A_bf16[M,1024] @ Bt[1024][1024] + bias
// 64x128 tile -> grid (8, 64) = 512 blocks. 12 KB LDS.
// =====================================================================
__global__ __launch_bounds__(256, 4) void gemm64(const u16* __restrict__ A,
                                                 const u16* __restrict__ Bt,
                                                 const float* __restrict__ bias,
                                                 float* __restrict__ C) {
    __shared__ u16 As[64 * 32];
    __shared__ u16 Bs[128 * 32];
    const int K = 1024;
    const int m0 = blockIdx.y * 64;
    const int n0 = blockIdx.x * 128;
    const int t = threadIdx.x;
    const int lane = t & 63;
    const int wid = t >> 6;
    const int wm = wid >> 1, wn = wid & 1;
    const int qd = lane >> 4, lm = lane & 15;

    const floatx4 zero4 = {0.f, 0.f, 0.f, 0.f};
    floatx4 acc[2][4];
#pragma unroll
    for (int i = 0; i < 2; i++)
#pragma unroll
        for (int j2 = 0; j2 < 4; j2++) acc[i][j2] = zero4;

    // staging: A tile 64x32 (8 elems/thread), B tile 128x32 (16 elems/thread)
    const int ar = t >> 2, ac_ = (t & 3) * 8;       // A row, col
    const int br = t >> 1, bc_ = (t & 1) * 16;      // B row, col
    const u16* Ap = A + (size_t)(m0 + ar) * K + ac_;
    const u16* Bp = Bt + (size_t)(n0 + br) * K + bc_;
    u16* awr = &As[ar * 32 + ac_];
    u16* bwr = &Bs[br * 32 + bc_];

    short8 pa0, pb0, pb1;
    pa0 = *(const short8*)Ap;
    pb0 = *(const short8*)Bp; pb1 = *(const short8*)(Bp + 8);

    for (int k0 = 0; k0 < K; k0 += 32) {
        __syncthreads();
        *(short8*)awr = pa0;
        *(short8*)bwr = pb0;
        *(short8*)(bwr + 8) = pb1;
        if (k0 + 32 < K) {
            Ap += 32; Bp += 32;
            pa0 = *(const short8*)Ap;
            pb0 = *(const short8*)Bp; pb1 = *(const short8*)(Bp + 8);
        }
        __syncthreads();

        short8 af[2], bfg[4];
#pragma unroll
        for (int i = 0; i < 2; i++)
            af[i] = *(const short8*)&As[(wm * 32 + i * 16 + lm) * 32 + qd * 8];
#pragma unroll
        for (int j2 = 0; j2 < 4; j2++)
            bfg[j2] = *(const short8*)&Bs[(wn * 64 + j2 * 16 + lm) * 32 + qd * 8];
#pragma unroll
        for (int i = 0; i < 2; i++)
#pragma unroll
            for (int j2 = 0; j2 < 4; j2++)
                acc[i][j2] = __builtin_amdgcn_mfma_f32_16x16x32_bf16(af[i], bfg[j2], acc[i][j2], 0, 0, 0);
    }

#pragma unroll
    for (int i = 0; i < 2; i++) {
        const int mb = m0 + wm * 32 + i * 16 + qd * 4;
#pragma unroll
        for (int j2 = 0; j2 < 4; j2++) {
            const int col = n0 + wn * 64 + j2 * 16 + lm;
            const float bv = bias[col];
#pragma unroll
            for (int r = 0; r < 4; r++)
                C[(size_t)(mb + r) * 1024 + col] = acc[i][j2][r] + bv;
        }
    }
}

// =====================================================================
// attention v4: split-K flash, wave = 64 q-rows, reg-prefetch dbuf.
// grid (8 qtiles, 32 bh, 2 splits). block 256 = 4 waves.
// =====================================================================
__global__ __launch_bounds__(256, 2) void attn4(
    const u16* __restrict__ Q, const u16* __restrict__ Kk,
    const u16* __restrict__ Vtg, float* __restrict__ ctxp,
    float* __restrict__ lp) {
    __shared__ u16 Ks[64 * 72];
    __shared__ u16 Vs[64 * 72];
    __shared__ u16 Ps[4 * 64 * 72];

    const int bh = blockIdx.y, b = bh >> 4, h = bh & 15;
    const int sp = blockIdx.z;
    const int base = b * 1024 + h * 64;
    const int t = threadIdx.x, lane = t & 63, w = t >> 6;
    const int qd = lane >> 4, lm = lane & 15;
    const int q0w = blockIdx.x * 256 + w * 64;      // wave's first q row

    short8 qf[4][2];
#pragma unroll
    for (int qh = 0; qh < 4; qh++) {
        const u16* qr = Q + (size_t)(q0w + qh * 16 + lm) * 2048 + base;
#pragma unroll
        for (int c = 0; c < 2; c++)
            qf[qh][c] = *(const short8*)(qr + c * 32 + qd * 8);
    }

    const floatx4 zero4 = {0.f, 0.f, 0.f, 0.f};
    floatx4 ctx[4][4];
#pragma unroll
    for (int qh = 0; qh < 4; qh++)
#pragma unroll
        for (int g = 0; g < 4; g++) ctx[qh][g] = zero4;
    float lpart[4] = {0.f, 0.f, 0.f, 0.f};

    u16* Pw = &Ps[w * 64 * 72];
    const float C = 0.18033688011112042f;   // log2(e)/sqrt(64)

    const int sr = t >> 3, sc = (t & 7) * 8;
    const u16* ksrc = Kk + (size_t)(sp * 1024 + sr) * 2048 + base + sc;
    const u16* vsrc = Vtg + ((size_t)bh * 64 + sr) * 2048 + sp * 1024 + sc;
    u16* kdst0 = &Ks[sr * 72 + sc];
    u16* kdst1 = &Ks[(sr + 32) * 72 + sc];
    u16* vdst0 = &Vs[sr * 72 + sc];
    u16* vdst1 = &Vs[(sr + 32) * 72 + sc];

    short8 ka0 = *(const short8*)ksrc;
    short8 ka1 = *(const short8*)(ksrc + (size_t)32 * 2048);
    short8 va0 = *(const short8*)vsrc;
    short8 va1 = *(const short8*)(vsrc + (size_t)32 * 2048);

    for (int kt = 0; kt < 16; kt++) {
        __syncthreads();
        *(short8*)kdst0 = ka0;
        *(short8*)kdst1 = ka1;
        *(short8*)vdst0 = va0;
        *(short8*)vdst1 = va1;
        __syncthreads();
        if (kt < 15) {
            ksrc += (size_t)64 * 2048;
            vsrc += 64;
            ka0 = *(const short8*)ksrc;
            ka1 = *(const short8*)(ksrc + (size_t)32 * 2048);
            va0 = *(const short8*)vsrc;
            va1 = *(const short8*)(vsrc + (size_t)32 * 2048);
        }

        // --- S^T = K.Q^T, exp, vectorized P store ---
#pragma unroll
        for (int g = 0; g < 4; g++) {
            const short8 kf0 = *(const short8*)&Ks[(g * 16 + lm) * 72 + qd * 8];
            const short8 kf1 = *(const short8*)&Ks[(g * 16 + lm) * 72 + 32 + qd * 8];
#pragma unroll
            for (int qh = 0; qh < 4; qh++) {
                floatx4 st = zero4;
                st = __builtin_amdgcn_mfma_f32_16x16x32_bf16(kf0, qf[qh][0], st, 0, 0, 0);
                st = __builtin_amdgcn_mfma_f32_16x16x32_bf16(kf1, qf[qh][1], st, 0, 0, 0);
                const float p0 = exp2f(st[0] * C);
                const float p1 = exp2f(st[1] * C);
                const float p2 = exp2f(st[2] * C);
                const float p3 = exp2f(st[3] * C);
                lpart[qh] += (p0 + p1) + (p2 + p3);
                uint2v pw;
                pw[0] = pk2bf(p0, p1);
                pw[1] = pk2bf(p2, p3);
                *(uint2v*)&Pw[(qh * 16 + lm) * 72 + g * 16 + qd * 4] = pw;
            }
        }

        // --- ctx += P.V ---
        short8 pa[4][2];
#pragma unroll
        for (int qh = 0; qh < 4; qh++)
#pragma unroll
            for (int c = 0; c < 2; c++)
                pa[qh][c] = *(const short8*)&Pw[(qh * 16 + lm) * 72 + c * 32 + qd * 8];
#pragma unroll
        for (int g = 0; g < 4; g++) {
            const short8 vb0 = *(const short8*)&Vs[(g * 16 + lm) * 72 + qd * 8];
            const short8 vb1 = *(const short8*)&Vs[(g * 16 + lm) * 72 + 32 + qd * 8];
#pragma unroll
            for (int qh = 0; qh < 4; qh++) {
                ctx[qh][g] = __builtin_amdgcn_mfma_f32_16x16x32_bf16(pa[qh][0], vb0, ctx[qh][g], 0, 0, 0);
                ctx[qh][g] = __builtin_amdgcn_mfma_f32_16x16x32_bf16(pa[qh][1], vb1, ctx[qh][g], 0, 0, 0);
            }
        }
    }

    float* cbase = ctxp + (size_t)sp * 4194304;
#pragma unroll
    for (int qh = 0; qh < 4; qh++) {
        float l = lpart[qh];
        l += __shfl_xor(l, 16);
        l += __shfl_xor(l, 32);
        if (lane < 16)
            lp[(size_t)sp * 65536 + bh * 2048 + q0w + qh * 16 + lane] = l;
#pragma unroll
        for (int r = 0; r < 4; r++) {
            const int srow = q0w + qh * 16 + qd * 4 + r;
            float* orow = cbase + (size_t)srow * 2048 + base;
#pragma unroll
            for (int g = 0; g < 4; g++)
                orow[g * 16 + lm] = ctx[qh][g][r];
        }
    }
}

// =====================================================================
// merge: out_bf16 = (ctx0 + ctx1) / (l0 + l1), elementwise over 4M
// =====================================================================
__global__ __launch_bounds__(256) void merge(const float* __restrict__ ctxp,
                                             const float* __restrict__ lp,
                                             u16* __restrict__ out) {
    const size_t idx = ((size_t)blockIdx.x * 256 + threadIdx.x) * 4;
    const floatx4 a = *(const floatx4*)(ctxp + idx);
    const floatx4 c = *(const floatx4*)(ctxp + 4194304 + idx);
    const int srow = (int)(idx >> 11);
    const int rem = (int)(idx & 2047);
    const int bh = rem >> 6;
    const float l = lp[bh * 2048 + srow] + lp[65536 + bh * 2048 + srow];
    const float inv = 1.0f / l;
    ushort4v o;
    const unsigned int lo = pk2bf((a[0] + c[0]) * inv, (a[1] + c[1]) * inv);
    const unsigned int hi = pk2bf((a[2] + c[2]) * inv, (a[3] + c[3]) * inv);
    o[0] = (u16)(lo & 0xffff); o[1] = (u16)(lo >> 16);
    o[2] = (u16)(hi & 0xffff); o[3] = (u16)(hi >> 16);
    *(ushort4v*)(out + idx) = o;
}

// =====================================================================
// host orchestration
// =====================================================================
extern "C" void kernel_launch(void* const* d_in, const int* in_sizes, int n_in,
                              void* d_out, int out_size, void* d_ws, size_t ws_size,
                              hipStream_t stream) {
    const float* qx = (const float*)d_in[0];
    const float* kx = (const float*)d_in[1];
    const float* vx = (const float*)d_in[2];
    const float* qc = (const float*)d_in[3];
    const float* kc = (const float*)d_in[4];
    const float* W_qx = (const float*)d_in[5];   const float* b_qx = (const float*)d_in[6];
    const float* W_kx = (const float*)d_in[7];   const float* b_kx = (const float*)d_in[8];
    const float* W_vx = (const float*)d_in[9];   const float* b_vx = (const float*)d_in[10];
    const float* W_qc = (const float*)d_in[11];  const float* b_qc = (const float*)d_in[12];
    const float* W_kc = (const float*)d_in[13];  const float* b_kc = (const float*)d_in[14];
    const float* W_out = (const float*)d_in[15]; const float* b_out = (const float*)d_in[16];
    const float* W_Vqx = (const float*)d_in[17]; const float* b_Vqx = (const float*)d_in[18];
    const float* W_Vqc = (const float*)d_in[19]; const float* b_Vqc = (const float*)d_in[20];
    const float* W_Vkx = (const float*)d_in[21]; const float* b_Vkx = (const float*)d_in[22];
    const float* W_Vkc = (const float*)d_in[23]; const float* b_Vkc = (const float*)d_in[24];

    char* ws = (char*)d_ws;
    const size_t MB = 1048576;
    // layout:
    //   0   .. 32 MB : ctxp fp32 partials (2 x 16 MB)
    //   32  .. 40 MB : Vtg bf16
    //   40  .. 52 MB : Wt[6] bf16
    //   52  .. 60 MB : Pv bf16
    //   60  .. 68 MB : qg bf16
    //   68  .. 76 MB : kg bf16
    //   76  .. 84 MB : ctxbf bf16
    //   84 MB+ : wfused 16KB+4 scalars, lam 32KB, l_part 512KB
    float* ctxp = (float*)ws;
    u16* Vtg    = (u16*)(ws + 32 * MB);
    u16* Wt[6];
    for (int i = 0; i < 6; i++) Wt[i] = (u16*)(ws + 40 * MB + (size_t)i * 2 * MB);
    u16* Pv    = (u16*)(ws + 52 * MB);
    u16* qg    = (u16*)(ws + 60 * MB);
    u16* kg    = (u16*)(ws + 68 * MB);
    u16* ctxbf = (u16*)(ws + 76 * MB);
    float* wfused = (float*)(ws + 84 * MB);                    // 4 x 1024
    float* bdot   = (float*)(ws + 84 * MB + 16384);            // 4 scalars
    float* lam    = (float*)(ws + 84 * MB + 16384 + 256);      // 2 x 4096
    float* l_part = (float*)(ws + 84 * MB + 16384 + 256 + 32768); // 2 x 32 x 2048

    // 1. fused gating weight vectors + bias-dot consts
    WFuseJobs wf;
    wf.W[0] = W_qx; wf.wv[0] = W_Vqx; wf.bl[0] = b_qx; wf.out[0] = wfused;
    wf.W[1] = W_qc; wf.wv[1] = W_Vqc; wf.bl[1] = b_qc; wf.out[1] = wfused + 1024;
    wf.W[2] = W_kx; wf.wv[2] = W_Vkx; wf.bl[2] = b_kx; wf.out[2] = wfused + 2048;
    wf.W[3] = W_kc; wf.wv[3] = W_Vkc; wf.bl[3] = b_kc; wf.out[3] = wfused + 3072;
    wf.bdot = bdot;
    wfuse<<<dim3(64, 4), 256, 0, stream>>>(wf);

    // 2. lambdas (row-dots + sigmoid, fp32 inputs direct)
    DotJobs dj;
    dj.xa[0] = qx; dj.xc[0] = qc; dj.w1[0] = wfused;        dj.w2[0] = wfused + 1024;
    dj.sA[0] = b_Vqx; dj.sB[0] = b_Vqc; dj.lam[0] = lam;
    dj.xa[1] = kx; dj.xc[1] = kc; dj.w1[1] = wfused + 2048; dj.w2[1] = wfused + 3072;
    dj.sA[1] = b_Vkx; dj.sB[1] = b_Vkc; dj.lam[1] = lam + 4096;
    dj.bdot = bdot;
    dotk<<<dim3(4096, 2), 256, 0, stream>>>(dj);

    // 3. transpose + cast weights
    WTJobs wj;
    const float* wsrc[6] = {W_qx, W_kx, W_vx, W_qc, W_kc, W_out};
    for (int i = 0; i < 6; i++) { wj.src[i] = wsrc[i]; wj.dst[i] = Wt[i]; }
    wtrans<<<dim3(32, 32, 6), 256, 0, stream>>>(wj);

    // 4. all projections in ONE launch, fp32-A reg-prefetch staging
    PJobs pj;
    pj.j[0].Aa = qx; pj.j[0].Ac = qc; pj.j[0].Ba = Wt[0]; pj.j[0].Bc = Wt[3];
    pj.j[0].biasA = b_qx; pj.j[0].biasC = b_qc; pj.j[0].lam = lam;        pj.j[0].out = qg;
    pj.j[1].Aa = kx; pj.j[1].Ac = kc; pj.j[1].Ba = Wt[1]; pj.j[1].Bc = Wt[4];
    pj.j[1].biasA = b_kx; pj.j[1].biasC = b_kc; pj.j[1].lam = lam + 4096; pj.j[1].out = kg;
    pj.j[2].Aa = vx; pj.j[2].Ac = nullptr; pj.j[2].Ba = Wt[2]; pj.j[2].Bc = nullptr;
    pj.j[2].biasA = b_vx; pj.j[2].biasC = nullptr; pj.j[2].lam = nullptr; pj.j[2].out = Pv;
    projall<<<dim3(8, 32, 3), 256, 0, stream>>>(pj);

    // 5. transpose V
    vtrans<<<dim3(64, 2, 32), 256, 0, stream>>>(Pv, Vtg);

    // 6. attention (split-K x2, 64 q/wave, reg-prefetch)
    attn4<<<dim3(8, 32, 2), 256, 0, stream>>>(qg, kg, Vtg, ctxp, l_part);

    // 7. merge partials -> ctx bf16
    merge<<<4096, 256, 0, stream>>>(ctxp, l_part, ctxbf);

    // 8. output projection -> d_out (fp32)
    gemm64<<<dim3(8, 64), 256, 0, stream>>>(ctxbf, Wt[5], b_out, (float*)d_out);
}

// Round 6
// 351.847 us; speedup vs baseline: 1.0815x; 1.0815x over previous
//
#include <hip/hip_runtime.h>
#include <math.h>

typedef unsigned short u16;
typedef __attribute__((ext_vector_type(8))) short short8;     // 8 bf16 = one MFMA A/B frag
typedef __attribute__((ext_vector_type(4))) float floatx4;    // MFMA C/D frag
typedef __attribute__((ext_vector_type(4))) unsigned short ushort4v;
typedef __attribute__((ext_vector_type(2))) unsigned int uint2v;

// ---------- bf16 helpers (raw u16, RNE) ----------
__device__ __forceinline__ float bf2f(u16 x) {
    union { unsigned int u; float f; } v; v.u = ((unsigned int)x) << 16; return v.f;
}
__device__ __forceinline__ u16 f2bf(float f) {
    union { float f; unsigned int u; } v; v.f = f;
    unsigned int r = v.u + 0x7fffu + ((v.u >> 16) & 1u);
    return (u16)(r >> 16);
}
__device__ __forceinline__ unsigned int pk2bf(float a, float b) {
#if __has_builtin(__builtin_amdgcn_cvt_pk_bf16_f32)
    auto r = __builtin_amdgcn_cvt_pk_bf16_f32(a, b);
    union { decltype(r) v; unsigned int u; } cv; cv.v = r; return cv.u;
#else
    return (unsigned int)f2bf(a) | ((unsigned int)f2bf(b) << 16);
#endif
}

// =====================================================================
// wfuse: w_z[row] = dot(W_z[row][:], wv_z[:]) ; block x==0 also emits
// bdot[z] = dot(bl_z, wv_z).  grid (64, 4).
// =====================================================================
struct WFuseJobs { const float* W[4]; const float* wv[4]; const float* bl[4];
                   float* out[4]; float* bdot; };

__global__ __launch_bounds__(256) void wfuse(WFuseJobs wf) {
    const int z = blockIdx.y;
    const float* W = wf.W[z];
    const float* wv = wf.wv[z];
    float* out = wf.out[z];
    const int t = threadIdx.x;
    const int lane = t & 63, w = t >> 6;
#pragma unroll
    for (int i = 0; i < 4; i++) {
        const int row = blockIdx.x * 16 + w * 4 + i;
        const float* Wr = W + (size_t)row * 1024 + lane * 16;
        const float* vr = wv + lane * 16;
        float p = 0.f;
#pragma unroll
        for (int c = 0; c < 4; c++) {
            const floatx4 a = *(const floatx4*)(Wr + c * 4);
            const floatx4 b = *(const floatx4*)(vr + c * 4);
            p += a[0] * b[0] + a[1] * b[1] + a[2] * b[2] + a[3] * b[3];
        }
#pragma unroll
        for (int m = 1; m <= 32; m <<= 1) p += __shfl_xor(p, m);
        if (lane == 0) out[row] = p;
    }
    if (blockIdx.x == 0) {
        const floatx4 bb = *(const floatx4*)(wf.bl[z] + t * 4);
        const floatx4 vv = *(const floatx4*)(wv + t * 4);
        float p = bb[0] * vv[0] + bb[1] * vv[1] + bb[2] * vv[2] + bb[3] * vv[3];
#pragma unroll
        for (int m = 1; m <= 32; m <<= 1) p += __shfl_xor(p, m);
        __shared__ float red[4];
        if ((t & 63) == 0) red[t >> 6] = p;
        __syncthreads();
        if (t == 0) wf.bdot[z] = red[0] + red[1] + red[2] + red[3];
    }
}

// =====================================================================
// gatecast: per row m, z<2: lam = sigmoid(xa.w1 + xc.w2 + consts);
//   write A'[m] = [(1-lam)*xa | lam*xc] bf16 (concat-K layout, stride 2048)
//   and lam[m] for the GEMM epilogue bias mix.
// z==2: plain cast vx -> bf16 (stride 1024).
// grid (4096, 3), block 256, 4 elems/thread.
// =====================================================================
struct GCJobs {
    const float* xa[3]; const float* xc[3];
    const float* w1[3]; const float* w2[3];
    const float* bdot;                 // 4 scalars
    const float* sA[3]; const float* sB[3];
    float* lamout[3];
    u16* dst[3];
};

__global__ __launch_bounds__(256) void gatecast(GCJobs gj) {
    const int z = blockIdx.y;
    const int row = blockIdx.x;
    const int t = threadIdx.x;
    const size_t off = (size_t)row * 1024 + t * 4;
    const floatx4 a = *(const floatx4*)(gj.xa[z] + off);

    if (z == 2) {
        ushort4v o;
        const unsigned int lo = pk2bf(a[0], a[1]);
        const unsigned int hi = pk2bf(a[2], a[3]);
        o[0] = (u16)(lo & 0xffff); o[1] = (u16)(lo >> 16);
        o[2] = (u16)(hi & 0xffff); o[3] = (u16)(hi >> 16);
        *(ushort4v*)(gj.dst[2] + (size_t)row * 1024 + t * 4) = o;
        return;
    }

    const floatx4 c  = *(const floatx4*)(gj.xc[z] + off);
    const floatx4 w1 = *(const floatx4*)(gj.w1[z] + t * 4);
    const floatx4 w2 = *(const floatx4*)(gj.w2[z] + t * 4);
    float p = 0.f;
#pragma unroll
    for (int j = 0; j < 4; j++) p += a[j] * w1[j] + c[j] * w2[j];
#pragma unroll
    for (int m = 1; m <= 32; m <<= 1) p += __shfl_xor(p, m);
    __shared__ float red[4];
    if ((t & 63) == 0) red[t >> 6] = p;
    __syncthreads();
    const float x = red[0] + red[1] + red[2] + red[3]
                  + gj.bdot[2 * z] + gj.bdot[2 * z + 1]
                  + gj.sA[z][0] + gj.sB[z][0];
    const float lam = 1.f / (1.f + exp2f(-x * 1.44269504f));
    if (t == 0) gj.lamout[z][row] = lam;
    const float oml = 1.f - lam;

    u16* d = gj.dst[z] + (size_t)row * 2048 + t * 4;
    ushort4v o1, o2;
    {
        const unsigned int lo = pk2bf(oml * a[0], oml * a[1]);
        const unsigned int hi = pk2bf(oml * a[2], oml * a[3]);
        o1[0] = (u16)(lo & 0xffff); o1[1] = (u16)(lo >> 16);
        o1[2] = (u16)(hi & 0xffff); o1[3] = (u16)(hi >> 16);
    }
    {
        const unsigned int lo = pk2bf(lam * c[0], lam * c[1]);
        const unsigned int hi = pk2bf(lam * c[2], lam * c[3]);
        o2[0] = (u16)(lo & 0xffff); o2[1] = (u16)(lo >> 16);
        o2[2] = (u16)(hi & 0xffff); o2[3] = (u16)(hi >> 16);
    }
    *(ushort4v*)d = o1;
    *(ushort4v*)(d + 1024) = o2;
}

// =====================================================================
// wtrans: W[k][n] fp32 -> Wt[n*stride + koff + k] bf16 (concat-K capable)
// =====================================================================
struct WTJobs { const float* src[6]; u16* dst[6]; int stride[6]; int koff[6]; };

__global__ __launch_bounds__(256) void wtrans(WTJobs wj) {
    __shared__ float tile[32][33];
    const int z = blockIdx.z;
    const float* W = wj.src[z];
    u16* Wt = wj.dst[z];
    const int stride = wj.stride[z], koff = wj.koff[z];
    const int n0 = blockIdx.x * 32, k0 = blockIdx.y * 32;
    const int tx = threadIdx.x & 31, ty = threadIdx.x >> 5;
#pragma unroll
    for (int i = 0; i < 4; i++)
        tile[ty + i * 8][tx] = W[(size_t)(k0 + ty + i * 8) * 1024 + n0 + tx];
    __syncthreads();
#pragma unroll
    for (int i = 0; i < 4; i++)
        Wt[(size_t)(n0 + ty + i * 8) * stride + koff + k0 + tx] = f2bf(tile[tx][ty + i * 8]);
}

// =====================================================================
// transpose V: V[s][base+d] (stride 2048) -> Vtg[(bh*64+d)*2048 + s], bf16
// =====================================================================
__global__ __launch_bounds__(256) void vtrans(const u16* __restrict__ V,
                                              u16* __restrict__ Vtg) {
    __shared__ u16 tile[32][34];
    const int bh = blockIdx.z, b = bh >> 4, h = bh & 15;
    const int base = b * 1024 + h * 64;
    const int s0 = blockIdx.x * 32, d0 = blockIdx.y * 32;
    const int tx = threadIdx.x & 31, ty = threadIdx.x >> 5;
#pragma unroll
    for (int i = 0; i < 4; i++)
        tile[ty + i * 8][tx] = V[(size_t)(s0 + ty + i * 8) * 2048 + base + d0 + tx];
    __syncthreads();
#pragma unroll
    for (int i = 0; i < 4; i++)
        Vtg[((size_t)bh * 64 + d0 + ty + i * 8) * 2048 + s0 + tx] = tile[tx][ty + i * 8];
}

// =====================================================================
// projall v3: single-accumulator GEMM, concat-K inputs, bf16 reg-prefetch.
// out_bf16[M,1024] = A[M,K] @ Bt[1024][K] (+ epilogue bias / lam-bias-mix)
// 128x128 tile, BK=32. grid (8, 32, 3): z=0 q (K=2048), z=1 k (K=2048),
// z=2 v (K=1024). LDS 16 KB, 3 blocks/CU.
// =====================================================================
struct PJob {
    const u16* A; const u16* Bt; int K;
    const float* biasA; const float* biasC; const float* lam; u16* out;
};
struct PJobs { PJob j[3]; };

__global__ __launch_bounds__(256, 3) void projall(PJobs jobs) {
    __shared__ u16 As[128 * 32];
    __shared__ u16 Bs[128 * 32];
    const PJob jb = jobs.j[blockIdx.z];
    const int K = jb.K;
    const int m0 = blockIdx.y * 128;
    const int n0 = blockIdx.x * 128;
    const int t = threadIdx.x;
    const int lane = t & 63;
    const int wid = t >> 6;
    const int wm = wid >> 1, wn = wid & 1;
    const int qd = lane >> 4, lm = lane & 15;

    const floatx4 zero4 = {0.f, 0.f, 0.f, 0.f};
    floatx4 acc[4][4];
#pragma unroll
    for (int i = 0; i < 4; i++)
#pragma unroll
        for (int j2 = 0; j2 < 4; j2++) acc[i][j2] = zero4;

    // staging: thread t covers row = t>>1, cols colb..colb+15 (16 u16 = 2x16B)
    const int srow = t >> 1, colb = (t & 1) * 16;
    const u16* Ap = jb.A + (size_t)(m0 + srow) * K + colb;
    const u16* Bp = jb.Bt + (size_t)(n0 + srow) * K + colb;
    u16* awr = &As[srow * 32 + colb];
    u16* bwr = &Bs[srow * 32 + colb];

    short8 pa0 = *(const short8*)Ap;
    short8 pa1 = *(const short8*)(Ap + 8);
    short8 pb0 = *(const short8*)Bp;
    short8 pb1 = *(const short8*)(Bp + 8);

    for (int k0 = 0; k0 < K; k0 += 32) {
        __syncthreads();
        *(short8*)awr       = pa0;
        *(short8*)(awr + 8) = pa1;
        *(short8*)bwr       = pb0;
        *(short8*)(bwr + 8) = pb1;
        if (k0 + 32 < K) {
            Ap += 32; Bp += 32;
            pa0 = *(const short8*)Ap;
            pa1 = *(const short8*)(Ap + 8);
            pb0 = *(const short8*)Bp;
            pb1 = *(const short8*)(Bp + 8);
        }
        __syncthreads();

        short8 af[4], bfg[4];
#pragma unroll
        for (int i = 0; i < 4; i++) {
            af[i]  = *(const short8*)&As[(wm * 64 + i * 16 + lm) * 32 + qd * 8];
            bfg[i] = *(const short8*)&Bs[(wn * 64 + i * 16 + lm) * 32 + qd * 8];
        }
#pragma unroll
        for (int i = 0; i < 4; i++)
#pragma unroll
            for (int j2 = 0; j2 < 4; j2++)
                acc[i][j2] = __builtin_amdgcn_mfma_f32_16x16x32_bf16(af[i], bfg[j2], acc[i][j2], 0, 0, 0);
    }

#pragma unroll
    for (int i = 0; i < 4; i++) {
        const int mb = m0 + wm * 64 + i * 16 + qd * 4;
        float lamv[4];
        if (jb.lam) {
#pragma unroll
            for (int r = 0; r < 4; r++) lamv[r] = jb.lam[mb + r];
        }
#pragma unroll
        for (int j2 = 0; j2 < 4; j2++) {
            const int col = n0 + wn * 64 + j2 * 16 + lm;
            const float bA = jb.biasA[col];
            if (jb.lam) {
                const float dB = jb.biasC[col] - bA;
#pragma unroll
                for (int r = 0; r < 4; r++)
                    jb.out[(size_t)(mb + r) * 1024 + col] = f2bf(acc[i][j2][r] + bA + lamv[r] * dB);
            } else {
#pragma unroll
                for (int r = 0; r < 4; r++)
                    jb.out[(size_t)(mb + r) * 1024 + col] = f2bf(acc[i][j2][r] + bA);
            }
        }
    }
}

// =====================================================================
// gemm64: C_f32[M,1024] = A_bf16[M,1024] @ Bt[1024][1024] + bias
// 64x128 tile -> grid (8, 64) = 512 blocks. 12 KB LDS.
// =====================================================================
__global__ __launch_bounds__(256, 4) void gemm64(const u16* __restrict__ A,
                                                 const u16* __restrict__ Bt,
                                                 const float* __restrict__ bias,
                                                 float* __restrict__ C) {
    __shared__ u16 As[64 * 32];
    __shared__ u16 Bs[128 * 32];
    const int K = 1024;
    const int m0 = blockIdx.y * 64;
    const int n0 = blockIdx.x * 128;
    const int t = threadIdx.x;
    const int lane = t & 63;
    const int wid = t >> 6;
    const int wm = wid >> 1, wn = wid & 1;
    const int qd = lane >> 4, lm = lane & 15;

    const floatx4 zero4 = {0.f, 0.f, 0.f, 0.f};
    floatx4 acc[2][4];
#pragma unroll
    for (int i = 0; i < 2; i++)
#pragma unroll
        for (int j2 = 0; j2 < 4; j2++) acc[i][j2] = zero4;

    const int ar = t >> 2, ac_ = (t & 3) * 8;
    const int br = t >> 1, bc_ = (t & 1) * 16;
    const u16* Ap = A + (size_t)(m0 + ar) * K + ac_;
    const u16* Bp = Bt + (size_t)(n0 + br) * K + bc_;
    u16* awr = &As[ar * 32 + ac_];
    u16* bwr = &Bs[br * 32 + bc_];

    short8 pa0, pb0, pb1;
    pa0 = *(const short8*)Ap;
    pb0 = *(const short8*)Bp; pb1 = *(const short8*)(Bp + 8);

    for (int k0 = 0; k0 < K; k0 += 32) {
        __syncthreads();
        *(short8*)awr = pa0;
        *(short8*)bwr = pb0;
        *(short8*)(bwr + 8) = pb1;
        if (k0 + 32 < K) {
            Ap += 32; Bp += 32;
            pa0 = *(const short8*)Ap;
            pb0 = *(const short8*)Bp; pb1 = *(const short8*)(Bp + 8);
        }
        __syncthreads();

        short8 af[2], bfg[4];
#pragma unroll
        for (int i = 0; i < 2; i++)
            af[i] = *(const short8*)&As[(wm * 32 + i * 16 + lm) * 32 + qd * 8];
#pragma unroll
        for (int j2 = 0; j2 < 4; j2++)
            bfg[j2] = *(const short8*)&Bs[(wn * 64 + j2 * 16 + lm) * 32 + qd * 8];
#pragma unroll
        for (int i = 0; i < 2; i++)
#pragma unroll
            for (int j2 = 0; j2 < 4; j2++)
                acc[i][j2] = __builtin_amdgcn_mfma_f32_16x16x32_bf16(af[i], bfg[j2], acc[i][j2], 0, 0, 0);
    }

#pragma unroll
    for (int i = 0; i < 2; i++) {
        const int mb = m0 + wm * 32 + i * 16 + qd * 4;
#pragma unroll
        for (int j2 = 0; j2 < 4; j2++) {
            const int col = n0 + wn * 64 + j2 * 16 + lm;
            const float bv = bias[col];
#pragma unroll
            for (int r = 0; r < 4; r++)
                C[(size_t)(mb + r) * 1024 + col] = acc[i][j2][r] + bv;
        }
    }
}

// =====================================================================
// attention v4: split-K flash, wave = 64 q-rows, reg-prefetch dbuf.
// grid (8 qtiles, 32 bh, 2 splits). block 256 = 4 waves.
// =====================================================================
__global__ __launch_bounds__(256, 2) void attn4(
    const u16* __restrict__ Q, const u16* __restrict__ Kk,
    const u16* __restrict__ Vtg, float* __restrict__ ctxp,
    float* __restrict__ lp) {
    __shared__ u16 Ks[64 * 72];
    __shared__ u16 Vs[64 * 72];
    __shared__ u16 Ps[4 * 64 * 72];

    const int bh = blockIdx.y, b = bh >> 4, h = bh & 15;
    const int sp = blockIdx.z;
    const int base = b * 1024 + h * 64;
    const int t = threadIdx.x, lane = t & 63, w = t >> 6;
    const int qd = lane >> 4, lm = lane & 15;
    const int q0w = blockIdx.x * 256 + w * 64;

    short8 qf[4][2];
#pragma unroll
    for (int qh = 0; qh < 4; qh++) {
        const u16* qr = Q + (size_t)(q0w + qh * 16 + lm) * 2048 + base;
#pragma unroll
        for (int c = 0; c < 2; c++)
            qf[qh][c] = *(const short8*)(qr + c * 32 + qd * 8);
    }

    const floatx4 zero4 = {0.f, 0.f, 0.f, 0.f};
    floatx4 ctx[4][4];
#pragma unroll
    for (int qh = 0; qh < 4; qh++)
#pragma unroll
        for (int g = 0; g < 4; g++) ctx[qh][g] = zero4;
    float lpart[4] = {0.f, 0.f, 0.f, 0.f};

    u16* Pw = &Ps[w * 64 * 72];
    const float C = 0.18033688011112042f;   // log2(e)/sqrt(64)

    const int sr = t >> 3, sc = (t & 7) * 8;
    const u16* ksrc = Kk + (size_t)(sp * 1024 + sr) * 2048 + base + sc;
    const u16* vsrc = Vtg + ((size_t)bh * 64 + sr) * 2048 + sp * 1024 + sc;
    u16* kdst0 = &Ks[sr * 72 + sc];
    u16* kdst1 = &Ks[(sr + 32) * 72 + sc];
    u16* vdst0 = &Vs[sr * 72 + sc];
    u16* vdst1 = &Vs[(sr + 32) * 72 + sc];

    short8 ka0 = *(const short8*)ksrc;
    short8 ka1 = *(const short8*)(ksrc + (size_t)32 * 2048);
    short8 va0 = *(const short8*)vsrc;
    short8 va1 = *(const short8*)(vsrc + (size_t)32 * 2048);

    for (int kt = 0; kt < 16; kt++) {
        __syncthreads();
        *(short8*)kdst0 = ka0;
        *(short8*)kdst1 = ka1;
        *(short8*)vdst0 = va0;
        *(short8*)vdst1 = va1;
        __syncthreads();
        if (kt < 15) {
            ksrc += (size_t)64 * 2048;
            vsrc += 64;
            ka0 = *(const short8*)ksrc;
            ka1 = *(const short8*)(ksrc + (size_t)32 * 2048);
            va0 = *(const short8*)vsrc;
            va1 = *(const short8*)(vsrc + (size_t)32 * 2048);
        }

#pragma unroll
        for (int g = 0; g < 4; g++) {
            const short8 kf0 = *(const short8*)&Ks[(g * 16 + lm) * 72 + qd * 8];
            const short8 kf1 = *(const short8*)&Ks[(g * 16 + lm) * 72 + 32 + qd * 8];
#pragma unroll
            for (int qh = 0; qh < 4; qh++) {
                floatx4 st = zero4;
                st = __builtin_amdgcn_mfma_f32_16x16x32_bf16(kf0, qf[qh][0], st, 0, 0, 0);
                st = __builtin_amdgcn_mfma_f32_16x16x32_bf16(kf1, qf[qh][1], st, 0, 0, 0);
                const float p0 = exp2f(st[0] * C);
                const float p1 = exp2f(st[1] * C);
                const float p2 = exp2f(st[2] * C);
                const float p3 = exp2f(st[3] * C);
                lpart[qh] += (p0 + p1) + (p2 + p3);
                uint2v pw;
                pw[0] = pk2bf(p0, p1);
                pw[1] = pk2bf(p2, p3);
                *(uint2v*)&Pw[(qh * 16 + lm) * 72 + g * 16 + qd * 4] = pw;
            }
        }

        short8 pa[4][2];
#pragma unroll
        for (int qh = 0; qh < 4; qh++)
#pragma unroll
            for (int c = 0; c < 2; c++)
                pa[qh][c] = *(const short8*)&Pw[(qh * 16 + lm) * 72 + c * 32 + qd * 8];
#pragma unroll
        for (int g = 0; g < 4; g++) {
            const short8 vb0 = *(const short8*)&Vs[(g * 16 + lm) * 72 + qd * 8];
            const short8 vb1 = *(const short8*)&Vs[(g * 16 + lm) * 72 + 32 + qd * 8];
#pragma unroll
            for (int qh = 0; qh < 4; qh++) {
                ctx[qh][g] = __builtin_amdgcn_mfma_f32_16x16x32_bf16(pa[qh][0], vb0, ctx[qh][g], 0, 0, 0);
                ctx[qh][g] = __builtin_amdgcn_mfma_f32_16x16x32_bf16(pa[qh][1], vb1, ctx[qh][g], 0, 0, 0);
            }
        }
    }

    float* cbase = ctxp + (size_t)sp * 4194304;
#pragma unroll
    for (int qh = 0; qh < 4; qh++) {
        float l = lpart[qh];
        l += __shfl_xor(l, 16);
        l += __shfl_xor(l, 32);
        if (lane < 16)
            lp[(size_t)sp * 65536 + bh * 2048 + q0w + qh * 16 + lane] = l;
#pragma unroll
        for (int r = 0; r < 4; r++) {
            const int srow = q0w + qh * 16 + qd * 4 + r;
            float* orow = cbase + (size_t)srow * 2048 + base;
#pragma unroll
            for (int g = 0; g < 4; g++)
                orow[g * 16 + lm] = ctx[qh][g][r];
        }
    }
}

// =====================================================================
// merge: out_bf16 = (ctx0 + ctx1) / (l0 + l1), elementwise over 4M
// =====================================================================
__global__ __launch_bounds__(256) void merge(const float* __restrict__ ctxp,
                                             const float* __restrict__ lp,
                                             u16* __restrict__ out) {
    const size_t idx = ((size_t)blockIdx.x * 256 + threadIdx.x) * 4;
    const floatx4 a = *(const floatx4*)(ctxp + idx);
    const floatx4 c = *(const floatx4*)(ctxp + 4194304 + idx);
    const int srow = (int)(idx >> 11);
    const int rem = (int)(idx & 2047);
    const int bh = rem >> 6;
    const float l = lp[bh * 2048 + srow] + lp[65536 + bh * 2048 + srow];
    const float inv = 1.0f / l;
    ushort4v o;
    const unsigned int lo = pk2bf((a[0] + c[0]) * inv, (a[1] + c[1]) * inv);
    const unsigned int hi = pk2bf((a[2] + c[2]) * inv, (a[3] + c[3]) * inv);
    o[0] = (u16)(lo & 0xffff); o[1] = (u16)(lo >> 16);
    o[2] = (u16)(hi & 0xffff); o[3] = (u16)(hi >> 16);
    *(ushort4v*)(out + idx) = o;
}

// =====================================================================
// host orchestration
// =====================================================================
extern "C" void kernel_launch(void* const* d_in, const int* in_sizes, int n_in,
                              void* d_out, int out_size, void* d_ws, size_t ws_size,
                              hipStream_t stream) {
    const float* qx = (const float*)d_in[0];
    const float* kx = (const float*)d_in[1];
    const float* vx = (const float*)d_in[2];
    const float* qc = (const float*)d_in[3];
    const float* kc = (const float*)d_in[4];
    const float* W_qx = (const float*)d_in[5];   const float* b_qx = (const float*)d_in[6];
    const float* W_kx = (const float*)d_in[7];   const float* b_kx = (const float*)d_in[8];
    const float* W_vx = (const float*)d_in[9];   const float* b_vx = (const float*)d_in[10];
    const float* W_qc = (const float*)d_in[11];  const float* b_qc = (const float*)d_in[12];
    const float* W_kc = (const float*)d_in[13];  const float* b_kc = (const float*)d_in[14];
    const float* W_out = (const float*)d_in[15]; const float* b_out = (const float*)d_in[16];
    const float* W_Vqx = (const float*)d_in[17]; const float* b_Vqx = (const float*)d_in[18];
    const float* W_Vqc = (const float*)d_in[19]; const float* b_Vqc = (const float*)d_in[20];
    const float* W_Vkx = (const float*)d_in[21]; const float* b_Vkx = (const float*)d_in[22];
    const float* W_Vkc = (const float*)d_in[23]; const float* b_Vkc = (const float*)d_in[24];

    char* ws = (char*)d_ws;
    const size_t MB = 1048576;
    // layout (aliases):
    //   0  .. 16 MB : Aq (concat-K q input)   | later ctxp[0] (fp32 partial 0)
    //   16 .. 32 MB : Ak                      | later ctxp[1]
    //   32 .. 40 MB : Av                      | later Vtg
    //   40 .. 44 MB : Wtq (1024 x 2048 bf16)
    //   44 .. 48 MB : Wtk
    //   48 .. 50 MB : Wtv (1024 x 1024 bf16)
    //   50 .. 52 MB : Wto
    //   52 .. 60 MB : Pv
    //   60 .. 68 MB : qg
    //   68 .. 76 MB : kg
    //   76 .. 84 MB : ctxbf
    //   84 MB+ : wfused 16KB, bdot, lam 32KB, l_part 512KB
    u16* Aq  = (u16*)ws;
    u16* Ak  = (u16*)(ws + 16 * MB);
    u16* Av  = (u16*)(ws + 32 * MB);
    u16* Wtq = (u16*)(ws + 40 * MB);
    u16* Wtk = (u16*)(ws + 44 * MB);
    u16* Wtv = (u16*)(ws + 48 * MB);
    u16* Wto = (u16*)(ws + 50 * MB);
    u16* Pv    = (u16*)(ws + 52 * MB);
    u16* qg    = (u16*)(ws + 60 * MB);
    u16* kg    = (u16*)(ws + 68 * MB);
    u16* ctxbf = (u16*)(ws + 76 * MB);
    float* wfused = (float*)(ws + 84 * MB);                       // 4 x 1024
    float* bdot   = (float*)(ws + 84 * MB + 16384);               // 4 scalars
    float* lam    = (float*)(ws + 84 * MB + 16384 + 256);         // 2 x 4096
    float* l_part = (float*)(ws + 84 * MB + 16384 + 256 + 32768); // 2 x 32 x 2048
    float* ctxp = (float*)ws;                  // aliases Aq/Ak (dead after projall)
    u16* Vtg    = (u16*)(ws + 32 * MB);        // aliases Av (dead after projall)

    // 1. fused gating weight vectors + bias-dot consts
    WFuseJobs wf;
    wf.W[0] = W_qx; wf.wv[0] = W_Vqx; wf.bl[0] = b_qx; wf.out[0] = wfused;
    wf.W[1] = W_qc; wf.wv[1] = W_Vqc; wf.bl[1] = b_qc; wf.out[1] = wfused + 1024;
    wf.W[2] = W_kx; wf.wv[2] = W_Vkx; wf.bl[2] = b_kx; wf.out[2] = wfused + 2048;
    wf.W[3] = W_kc; wf.wv[3] = W_Vkc; wf.bl[3] = b_kc; wf.out[3] = wfused + 3072;
    wf.bdot = bdot;
    wfuse<<<dim3(64, 4), 256, 0, stream>>>(wf);

    // 2. gatecast: lambdas + scaled concat-K bf16 A matrices + v cast
    GCJobs gj;
    gj.xa[0] = qx; gj.xc[0] = qc; gj.w1[0] = wfused;        gj.w2[0] = wfused + 1024;
    gj.sA[0] = b_Vqx; gj.sB[0] = b_Vqc; gj.lamout[0] = lam;        gj.dst[0] = Aq;
    gj.xa[1] = kx; gj.xc[1] = kc; gj.w1[1] = wfused + 2048; gj.w2[1] = wfused + 3072;
    gj.sA[1] = b_Vkx; gj.sB[1] = b_Vkc; gj.lamout[1] = lam + 4096; gj.dst[1] = Ak;
    gj.xa[2] = vx; gj.xc[2] = nullptr; gj.w1[2] = nullptr; gj.w2[2] = nullptr;
    gj.sA[2] = nullptr; gj.sB[2] = nullptr; gj.lamout[2] = nullptr; gj.dst[2] = Av;
    gj.bdot = bdot;
    gatecast<<<dim3(4096, 3), 256, 0, stream>>>(gj);

    // 3. transpose + cast weights into concat-K layouts
    WTJobs wj;
    wj.src[0] = W_qx; wj.dst[0] = Wtq; wj.stride[0] = 2048; wj.koff[0] = 0;
    wj.src[1] = W_qc; wj.dst[1] = Wtq; wj.stride[1] = 2048; wj.koff[1] = 1024;
    wj.src[2] = W_kx; wj.dst[2] = Wtk; wj.stride[2] = 2048; wj.koff[2] = 0;
    wj.src[3] = W_kc; wj.dst[3] = Wtk; wj.stride[3] = 2048; wj.koff[3] = 1024;
    wj.src[4] = W_vx; wj.dst[4] = Wtv; wj.stride[4] = 1024; wj.koff[4] = 0;
    wj.src[5] = W_out; wj.dst[5] = Wto; wj.stride[5] = 1024; wj.koff[5] = 0;
    wtrans<<<dim3(32, 32, 6), 256, 0, stream>>>(wj);

    // 4. projections: q (K=2048), k (K=2048), v (K=1024) in one launch
    PJobs pj;
    pj.j[0].A = Aq; pj.j[0].Bt = Wtq; pj.j[0].K = 2048;
    pj.j[0].biasA = b_qx; pj.j[0].biasC = b_qc; pj.j[0].lam = lam;        pj.j[0].out = qg;
    pj.j[1].A = Ak; pj.j[1].Bt = Wtk; pj.j[1].K = 2048;
    pj.j[1].biasA = b_kx; pj.j[1].biasC = b_kc; pj.j[1].lam = lam + 4096; pj.j[1].out = kg;
    pj.j[2].A = Av; pj.j[2].Bt = Wtv; pj.j[2].K = 1024;
    pj.j[2].biasA = b_vx; pj.j[2].biasC = nullptr; pj.j[2].lam = nullptr; pj.j[2].out = Pv;
    projall<<<dim3(8, 32, 3), 256, 0, stream>>>(pj);

    // 5. transpose V (Av dead -> Vtg aliases it)
    vtrans<<<dim3(64, 2, 32), 256, 0, stream>>>(Pv, Vtg);

    // 6. attention (split-K x2, 64 q/wave, reg-prefetch); ctxp aliases Aq/Ak
    attn4<<<dim3(8, 32, 2), 256, 0, stream>>>(qg, kg, Vtg, ctxp, l_part);

    // 7. merge partials -> ctx bf16
    merge<<<4096, 256, 0, stream>>>(ctxp, l_part, ctxbf);

    // 8. output projection -> d_out (fp32)
    gemm64<<<dim3(8, 64), 256, 0, stream>>>(ctxbf, Wto, b_out, (float*)d_out);
}